// Round 1
// baseline (941.498 us; speedup 1.0000x reference)
//
#include <hip/hip_runtime.h>
#include <math.h>

#define BB   32
#define NN   64
#define NGG  100
#define NBB  128
#define NFF  256
#define NITER 3
#define JB   16

// ---------------- embed: X[b,n,:] = W_emb[Z[b,n],:] ----------------
__global__ void embed_kernel(const int* __restrict__ Z, const float* __restrict__ W_emb,
                             float* __restrict__ X) {
    int bn = blockIdx.x, t = threadIdx.x;
    X[bn * NBB + t] = W_emb[Z[bn] * NBB + t];
}

// ---------------- fX = X @ Wi + bi  [B,N,NF] ----------------
__global__ void fx_kernel(const float* __restrict__ X, const float* __restrict__ Wi,
                          const float* __restrict__ bi, float* __restrict__ fX) {
    __shared__ float Xs[NBB];
    int bn = blockIdx.x, t = threadIdx.x;
    if (t < NBB) Xs[t] = X[bn * NBB + t];
    __syncthreads();
    float acc = bi[t];
    for (int k = 0; k < NBB; ++k) acc += Xs[k] * Wi[k * NFF + t];
    fX[bn * NFF + t] = acc;
}

// ---------------- interaction: X[b,i,:] += sum_j mask * tanh((fX[b,j]*fC[b,i,j]) @ Wf)
// one block per (b,i); 128 threads; j blocked by JB=16
__global__ __launch_bounds__(128) void interact_kernel(
    const int* __restrict__ Z, const float* __restrict__ C,
    const float* __restrict__ Wc, const float* __restrict__ bc,
    const float* __restrict__ Wf, const float* __restrict__ fX,
    float* __restrict__ X)
{
    __shared__ float Cs[JB * NGG];      // 6400 B, C tile (contiguous rows)
    __shared__ float fVs[JB][NFF];      // 16384 B
    __shared__ float Vred[4][NBB];      // 2048 B

    int bi_ = blockIdx.x;
    int b = bi_ >> 6, i = bi_ & 63;
    int t = threadIdx.x;

    if (Z[b * NN + i] == 0) return;     // mask row all-zero -> X unchanged (block-uniform)

    int sub = t & 31;   // phase1: f-group (8 f's); phase2: o-group (4 o's)
    int grp = t >> 5;   // jj-group (4 jj's)

    float sred[4] = {0.f, 0.f, 0.f, 0.f};   // V accumulator for o = sub*4+q, summed over all j

    for (int j0 = 0; j0 < NN; j0 += JB) {
        // ---- stage C tile: rows j0..j0+15, contiguous 1600 floats ----
        const float* Cb = C + ((size_t)bi_ * NN + j0) * NGG;
        for (int idx = t; idx < JB * NGG; idx += 128) Cs[idx] = Cb[idx];
        __syncthreads();

        // ---- phase 1: fVs[jj][f] = (C_row . Wc[:,f] + bc[f]) * fX[b,j,f]
        {
            int f0 = sub * 8;
            float acc[4][8];
            float4 bca = *(const float4*)&bc[f0];
            float4 bcb = *(const float4*)&bc[f0 + 4];
            #pragma unroll
            for (int r = 0; r < 4; ++r) {
                acc[r][0] = bca.x; acc[r][1] = bca.y; acc[r][2] = bca.z; acc[r][3] = bca.w;
                acc[r][4] = bcb.x; acc[r][5] = bcb.y; acc[r][6] = bcb.z; acc[r][7] = bcb.w;
            }
            for (int g = 0; g < NGG; ++g) {
                float4 wa = *(const float4*)&Wc[g * NFF + f0];
                float4 wb = *(const float4*)&Wc[g * NFF + f0 + 4];
                float w[8] = {wa.x, wa.y, wa.z, wa.w, wb.x, wb.y, wb.z, wb.w};
                #pragma unroll
                for (int r = 0; r < 4; ++r) {
                    float c = Cs[(grp * 4 + r) * NGG + g];
                    #pragma unroll
                    for (int q = 0; q < 8; ++q) acc[r][q] += c * w[q];
                }
            }
            #pragma unroll
            for (int r = 0; r < 4; ++r) {
                int j = j0 + grp * 4 + r;
                const float* fxp = &fX[(size_t)(b * NN + j) * NFF + f0];
                float4 xa = *(const float4*)fxp;
                float4 xb = *(const float4*)(fxp + 4);
                float x[8] = {xa.x, xa.y, xa.z, xa.w, xb.x, xb.y, xb.z, xb.w};
                float4 oa, ob;
                oa.x = acc[r][0] * x[0]; oa.y = acc[r][1] * x[1];
                oa.z = acc[r][2] * x[2]; oa.w = acc[r][3] * x[3];
                ob.x = acc[r][4] * x[4]; ob.y = acc[r][5] * x[5];
                ob.z = acc[r][6] * x[6]; ob.w = acc[r][7] * x[7];
                *(float4*)&fVs[grp * 4 + r][f0]     = oa;
                *(float4*)&fVs[grp * 4 + r][f0 + 4] = ob;
            }
        }
        __syncthreads();

        // ---- phase 2: pre[jj][o] = fVs[jj][:] @ Wf[:,o]; register tile 4jj x 4o
        {
            float pre[4][4];
            #pragma unroll
            for (int r = 0; r < 4; ++r)
                #pragma unroll
                for (int q = 0; q < 4; ++q) pre[r][q] = 0.f;

            for (int f = 0; f < NFF; f += 2) {
                float4 wA = *(const float4*)&Wf[(size_t)f * NBB + sub * 4];
                float4 wB = *(const float4*)&Wf[(size_t)(f + 1) * NBB + sub * 4];
                #pragma unroll
                for (int r = 0; r < 4; ++r) {
                    float2 v = *(const float2*)&fVs[grp * 4 + r][f];
                    pre[r][0] += v.x * wA.x; pre[r][1] += v.x * wA.y;
                    pre[r][2] += v.x * wA.z; pre[r][3] += v.x * wA.w;
                    pre[r][0] += v.y * wB.x; pre[r][1] += v.y * wB.y;
                    pre[r][2] += v.y * wB.z; pre[r][3] += v.y * wB.w;
                }
            }
            #pragma unroll
            for (int r = 0; r < 4; ++r) {
                int j = j0 + grp * 4 + r;
                int zj = Z[b * NN + j];
                if (zj > 0 && j != i) {
                    #pragma unroll
                    for (int q = 0; q < 4; ++q) sred[q] += tanhf(pre[r][q]);
                }
            }
        }
        __syncthreads();   // fVs/Cs safe to overwrite next iteration
    }

    // ---- reduce the 4 jj-groups ----
    #pragma unroll
    for (int q = 0; q < 4; ++q) Vred[grp][sub * 4 + q] = sred[q];
    __syncthreads();
    float v = Vred[0][t] + Vred[1][t] + Vred[2][t] + Vred[3][t];
    X[(size_t)bi_ * NBB + t] += v;
}

// ---------------- readout stage A: yi[b,i] = mask * (tanh(X@W1+b1)@W2 + b2)
__global__ void readoutA_kernel(const int* __restrict__ Z, const float* __restrict__ X,
                                const float* __restrict__ W1, const float* __restrict__ b1,
                                const float* __restrict__ W2, const float* __restrict__ b2,
                                float* __restrict__ yi_buf)
{
    __shared__ float Xs[NBB];
    int bn = blockIdx.x;      // b*N + i
    int h = threadIdx.x;      // 0..63
    Xs[h] = X[(size_t)bn * NBB + h];
    Xs[h + 64] = X[(size_t)bn * NBB + h + 64];
    __syncthreads();

    float s = b1[h];
    for (int k = 0; k < NBB; ++k) s += Xs[k] * W1[k * 64 + h];
    float v = tanhf(s) * W2[h];
    #pragma unroll
    for (int off = 32; off > 0; off >>= 1) v += __shfl_down(v, off);
    if (h == 0) {
        int z = Z[bn];
        yi_buf[bn] = (z > 0) ? (v + b2[0]) : 0.f;
    }
}

// ---------------- readout stage B: y[b] = sum_i yi[b,i]  (deterministic)
__global__ void readoutB_kernel(const float* __restrict__ yi_buf, float* __restrict__ y)
{
    int b = blockIdx.x, i = threadIdx.x;
    float v = yi_buf[b * NN + i];
    #pragma unroll
    for (int off = 32; off > 0; off >>= 1) v += __shfl_down(v, off);
    if (i == 0) y[b] = v;
}

extern "C" void kernel_launch(void* const* d_in, const int* in_sizes, int n_in,
                              void* d_out, int out_size, void* d_ws, size_t ws_size,
                              hipStream_t stream) {
    (void)in_sizes; (void)n_in; (void)out_size; (void)ws_size;
    const int*   Z    = (const int*)d_in[0];
    const float* C    = (const float*)d_in[1];
    const float* Wemb = (const float*)d_in[2];
    const float* Wc   = (const float*)d_in[3];
    const float* bc   = (const float*)d_in[4];
    const float* Wi   = (const float*)d_in[5];
    const float* bi   = (const float*)d_in[6];
    const float* Wf   = (const float*)d_in[7];
    const float* W1   = (const float*)d_in[8];
    const float* b1   = (const float*)d_in[9];
    const float* W2   = (const float*)d_in[10];
    const float* b2   = (const float*)d_in[11];
    float* y = (float*)d_out;

    // workspace layout (floats): X [B*N*NB] | fX [B*N*NF] | yi [B*N]
    float* X  = (float*)d_ws;
    float* fX = X + (size_t)BB * NN * NBB;
    float* yi = fX + (size_t)BB * NN * NFF;

    embed_kernel<<<BB * NN, NBB, 0, stream>>>(Z, Wemb, X);
    for (int it = 0; it < NITER; ++it) {
        fx_kernel<<<BB * NN, NFF, 0, stream>>>(X, Wi, bi, fX);
        interact_kernel<<<BB * NN, 128, 0, stream>>>(Z, C, Wc, bc, Wf, fX, X);
    }
    readoutA_kernel<<<BB * NN, 64, 0, stream>>>(Z, X, W1, b1, W2, b2, yi);
    readoutB_kernel<<<BB, NN, 0, stream>>>(yi, y);
}

// Round 2
// 251.782 us; speedup vs baseline: 3.7393x; 3.7393x over previous
//
#include <hip/hip_runtime.h>
#include <hip/hip_bf16.h>
#include <math.h>

#define BB   32
#define NN   64
#define NGG  100
#define NBB  128
#define NFF  256
#define NITER 3
#define KPAD 128   // NG=100 padded to MFMA K multiple

typedef __attribute__((ext_vector_type(8))) short short8;
typedef __attribute__((ext_vector_type(4))) float f32x4;

__device__ __forceinline__ unsigned short f2bf(float f) {
    __hip_bfloat16 h = __float2bfloat16(f);
    return *reinterpret_cast<unsigned short*>(&h);
}
__device__ __forceinline__ float bf2f(unsigned short u) {
    union { unsigned int i; float f; } v; v.i = ((unsigned int)u) << 16; return v.f;
}

// ---------------- embed: X[b,n,:] = W_emb[Z[b,n],:] ----------------
__global__ void embed_kernel(const int* __restrict__ Z, const float* __restrict__ W_emb,
                             float* __restrict__ X) {
    int bn = blockIdx.x, t = threadIdx.x;
    X[bn * NBB + t] = W_emb[Z[bn] * NBB + t];
}

// ---------------- transpose + pad + bf16: dst[c*Kpad+k] = k<K ? src[k*NC+c] : 0 ----------------
__global__ void transpose_pad_kernel(const float* __restrict__ src, unsigned short* __restrict__ dst,
                                     int K, int Kpad, int NC) {
    int idx = blockIdx.x * 256 + threadIdx.x;
    if (idx >= NC * Kpad) return;
    int c = idx / Kpad, k = idx - c * Kpad;
    dst[idx] = (k < K) ? f2bf(src[(size_t)k * NC + c]) : (unsigned short)0;
}

// ---------------- fX = X @ Wi + bi -> bf16 [B*N, NF] ----------------
__global__ void fx_kernel(const float* __restrict__ X, const float* __restrict__ Wi,
                          const float* __restrict__ bi, unsigned short* __restrict__ fXb) {
    __shared__ float Xs[NBB];
    int bn = blockIdx.x, t = threadIdx.x;
    if (t < NBB) Xs[t] = X[bn * NBB + t];
    __syncthreads();
    float acc = bi[t];
    for (int k = 0; k < NBB; ++k) acc += Xs[k] * Wi[k * NFF + t];
    fXb[bn * NFF + t] = f2bf(acc);
}

// ---------------- interaction (MFMA):
// per (b,i): fC = C[b,i]@Wc + bc ; fV = fX ⊙ fC ; pre = fV@Wf ; X[b,i] += Σ_j mask·tanh(pre)
__global__ __launch_bounds__(256) void interact_kernel(
    const int* __restrict__ Z, const float* __restrict__ C,
    const unsigned short* __restrict__ WcT, const float* __restrict__ bc,
    const unsigned short* __restrict__ WfT, const unsigned short* __restrict__ fXb,
    float* __restrict__ X)
{
    __shared__ __align__(16) unsigned short Cs[64 * KPAD];  // 16 KB, XOR-swizzled
    __shared__ __align__(16) unsigned short fVs[64 * NFF];  // 32 KB, XOR-swizzled
    __shared__ float msk[64];

    const int bi_ = blockIdx.x;
    const int b = bi_ >> 6, i = bi_ & 63;
    const int t = threadIdx.x;
    if (Z[b * NN + i] == 0) return;   // block-uniform: row i contributes nothing, X row unchanged

    const int wave = t >> 6, lane = t & 63;
    const int l15 = lane & 15, kg = lane >> 4;

    if (t < 64) msk[t] = (Z[b * NN + t] > 0 && t != i) ? 1.f : 0.f;

    // ---- stage C tile: 64 rows x 100 g (fp32 -> bf16, zero-pad to 128, swizzled) ----
    {
        int r = t >> 2, q = t & 3;
        const float* Crow = C + ((size_t)bi_ * NN + r) * NGG;   // 400B rows: 16B-aligned
        int sw = (r & 7) << 3;
        #pragma unroll
        for (int m = 0; m < 8; ++m) {
            int k = q * 32 + m * 4;
            ushort4 u;
            if (k < NGG) {
                float4 v = *(const float4*)(Crow + k);
                u.x = f2bf(v.x); u.y = f2bf(v.y); u.z = f2bf(v.z); u.w = f2bf(v.w);
            } else {
                u = make_ushort4(0, 0, 0, 0);
            }
            *(ushort4*)&Cs[r * KPAD + (k ^ sw)] = u;   // XOR hits bits 3-5 only; 4-chunk stays intact
        }
    }
    __syncthreads();

    // ---- phase A: fC tile via MFMA; wave w owns factor-cols [64w, 64w+64) ----
    {
        short8 bw[4][4];   // Wc B-frags, register-resident
        #pragma unroll
        for (int ct = 0; ct < 4; ++ct)
            #pragma unroll
            for (int ks = 0; ks < 4; ++ks)
                bw[ct][ks] = *(const short8*)&WcT[(size_t)(wave * 64 + ct * 16 + l15) * KPAD + ks * 32 + kg * 8];
        float bcv[4];
        #pragma unroll
        for (int ct = 0; ct < 4; ++ct) bcv[ct] = bc[wave * 64 + ct * 16 + l15];

        #pragma unroll
        for (int rt = 0; rt < 4; ++rt) {
            f32x4 acc[4];
            #pragma unroll
            for (int ct = 0; ct < 4; ++ct) {
                acc[ct][0] = bcv[ct]; acc[ct][1] = bcv[ct];
                acc[ct][2] = bcv[ct]; acc[ct][3] = bcv[ct];
            }
            const int r = rt * 16 + l15;
            const int sw = (r & 7) << 3;
            #pragma unroll
            for (int ks = 0; ks < 4; ++ks) {
                short8 af = *(const short8*)&Cs[r * KPAD + ((ks * 32 + kg * 8) ^ sw)];
                #pragma unroll
                for (int ct = 0; ct < 4; ++ct)
                    acc[ct] = __builtin_amdgcn_mfma_f32_16x16x32_bf16(af, bw[ct][ks], acc[ct], 0, 0, 0);
            }
            // D layout: col = l15, row = kg*4 + reg  ->  j = rt*16 + kg*4 + reg
            #pragma unroll
            for (int ct = 0; ct < 4; ++ct) {
                int c = wave * 64 + ct * 16 + l15;
                #pragma unroll
                for (int reg = 0; reg < 4; ++reg) {
                    int j = rt * 16 + kg * 4 + reg;
                    float fx = bf2f(fXb[((size_t)b * NN + j) * NFF + c]);
                    fVs[j * NFF + (c ^ ((j & 7) << 3))] = f2bf(acc[ct][reg] * fx);
                }
            }
        }
    }
    __syncthreads();

    // ---- phase B: pre = fV @ Wf via MFMA; wave w owns out-cols [32w, 32w+32) ----
    {
        short8 bwf[2][8];
        #pragma unroll
        for (int ct = 0; ct < 2; ++ct)
            #pragma unroll
            for (int ks = 0; ks < 8; ++ks)
                bwf[ct][ks] = *(const short8*)&WfT[(size_t)(wave * 32 + ct * 16 + l15) * NFF + ks * 32 + kg * 8];

        float vsum0 = 0.f, vsum1 = 0.f;
        #pragma unroll
        for (int jt = 0; jt < 4; ++jt) {
            f32x4 a0 = {0.f, 0.f, 0.f, 0.f}, a1 = {0.f, 0.f, 0.f, 0.f};
            const int r = jt * 16 + l15;
            const int sw = (r & 7) << 3;
            #pragma unroll
            for (int ks = 0; ks < 8; ++ks) {
                short8 af = *(const short8*)&fVs[r * NFF + ((ks * 32 + kg * 8) ^ sw)];
                a0 = __builtin_amdgcn_mfma_f32_16x16x32_bf16(af, bwf[0][ks], a0, 0, 0, 0);
                a1 = __builtin_amdgcn_mfma_f32_16x16x32_bf16(af, bwf[1][ks], a1, 0, 0, 0);
            }
            #pragma unroll
            for (int reg = 0; reg < 4; ++reg) {
                int j = jt * 16 + kg * 4 + reg;
                float m = msk[j];
                vsum0 += m * tanhf(a0[reg]);
                vsum1 += m * tanhf(a1[reg]);
            }
        }
        // reduce over the 4 row-groups (lane bits 4,5)
        vsum0 += __shfl_xor(vsum0, 16); vsum0 += __shfl_xor(vsum0, 32);
        vsum1 += __shfl_xor(vsum1, 16); vsum1 += __shfl_xor(vsum1, 32);
        if (lane < 16) {
            float* Xp = X + (size_t)bi_ * NBB + wave * 32 + lane;
            Xp[0]  += vsum0;
            Xp[16] += vsum1;
        }
    }
}

// ---------------- readout stage A ----------------
__global__ void readoutA_kernel(const int* __restrict__ Z, const float* __restrict__ X,
                                const float* __restrict__ W1, const float* __restrict__ b1,
                                const float* __restrict__ W2, const float* __restrict__ b2,
                                float* __restrict__ yi_buf)
{
    __shared__ float Xs[NBB];
    int bn = blockIdx.x;
    int h = threadIdx.x;      // 0..63
    Xs[h] = X[(size_t)bn * NBB + h];
    Xs[h + 64] = X[(size_t)bn * NBB + h + 64];
    __syncthreads();

    float s = b1[h];
    for (int k = 0; k < NBB; ++k) s += Xs[k] * W1[k * 64 + h];
    float v = tanhf(s) * W2[h];
    #pragma unroll
    for (int off = 32; off > 0; off >>= 1) v += __shfl_down(v, off);
    if (h == 0) {
        int z = Z[bn];
        yi_buf[bn] = (z > 0) ? (v + b2[0]) : 0.f;
    }
}

// ---------------- readout stage B ----------------
__global__ void readoutB_kernel(const float* __restrict__ yi_buf, float* __restrict__ y)
{
    int b = blockIdx.x, i = threadIdx.x;
    float v = yi_buf[b * NN + i];
    #pragma unroll
    for (int off = 32; off > 0; off >>= 1) v += __shfl_down(v, off);
    if (i == 0) y[b] = v;
}

extern "C" void kernel_launch(void* const* d_in, const int* in_sizes, int n_in,
                              void* d_out, int out_size, void* d_ws, size_t ws_size,
                              hipStream_t stream) {
    (void)in_sizes; (void)n_in; (void)out_size; (void)ws_size;
    const int*   Z    = (const int*)d_in[0];
    const float* C    = (const float*)d_in[1];
    const float* Wemb = (const float*)d_in[2];
    const float* Wc   = (const float*)d_in[3];
    const float* bc   = (const float*)d_in[4];
    const float* Wi   = (const float*)d_in[5];
    const float* bi   = (const float*)d_in[6];
    const float* Wf   = (const float*)d_in[7];
    const float* W1   = (const float*)d_in[8];
    const float* b1   = (const float*)d_in[9];
    const float* W2   = (const float*)d_in[10];
    const float* b2   = (const float*)d_in[11];
    float* y = (float*)d_out;

    // ws layout: X f32 [2048*128] | fXb bf16 [2048*256] | WcT bf16 [256*128] | WfT bf16 [128*256] | yi f32 [2048]
    float* X = (float*)d_ws;
    unsigned short* fXb = (unsigned short*)(X + (size_t)BB * NN * NBB);
    unsigned short* WcT = fXb + (size_t)BB * NN * NFF;
    unsigned short* WfT = WcT + (size_t)NFF * KPAD;
    float* yi = (float*)(WfT + (size_t)NBB * NFF);

    embed_kernel<<<BB * NN, NBB, 0, stream>>>(Z, Wemb, X);
    transpose_pad_kernel<<<(NFF * KPAD) / 256, 256, 0, stream>>>(Wc, WcT, NGG, KPAD, NFF);
    transpose_pad_kernel<<<(NBB * NFF) / 256, 256, 0, stream>>>(Wf, WfT, NFF, NFF, NBB);

    for (int it = 0; it < NITER; ++it) {
        fx_kernel<<<BB * NN, NFF, 0, stream>>>(X, Wi, bi, fXb);
        interact_kernel<<<BB * NN, 256, 0, stream>>>(Z, C, WcT, bc, WfT, fXb, X);
    }
    readoutA_kernel<<<BB * NN, 64, 0, stream>>>(Z, X, W1, b1, W2, b2, yi);
    readoutB_kernel<<<BB, NN, 0, stream>>>(yi, y);
}